// Round 3
// baseline (880.787 us; speedup 1.0000x reference)
//
#include <hip/hip_runtime.h>
#include <hip/hip_bf16.h>

#define N_NODES 100000
#define N_EDGES 3200000
#define F_IN 128
#define HID 16
#define N_CLASSES 32
#define N_RELS 20
#define BN_EPS 1e-5f
#define N_CELLS (N_NODES * N_RELS)          // 2,000,000
#define SCAN_NB ((N_CELLS + 2047) / 2048)   // 977

// ---------------- workspace layout (bytes), peak 97.7 MB ----------------
#define OFF_CS    0ull                  // int[N_CELLS]          8,000,000 (count -> scan -> destructive scatter)
#define OFF_REC   8000000ull            // u32[E] 12,800,000 ; overlaid by buf2 (float[N*32]) after conv2_agg
#define OFF_AGG1  20800000ull           // float[N*16]           6,400,000
#define OFF_BSUM  27200000ull           // int[1024]                 4,096
#define OFF_ST1   27204096ull           // float[32]                   256
#define OFF_ST2   27204352ull           // float[64]                   256
#define OFF_WT    27204608ull           // bf16[21*16*128]          86,016
#define OFF_W2T   27290624ull           // bf16[11*32*32]           22,528
#define OFF_X     27313152ull           // bf16 regionX: 22 slots x [N*16] = 70,400,000 -> 97,713,152
#define SLOT_BYTES 3200000ull           // one [N][16] bf16 slot

typedef __attribute__((ext_vector_type(8))) short bf16x8;
typedef __attribute__((ext_vector_type(4))) float f32x4;

__device__ inline short f2bf(float f) {
    union { __hip_bfloat16 h; short s; } u;
    u.h = __float2bfloat16(f);
    return u.s;
}

// ---------------- CSR build ----------------

__global__ void count_kernel(const int* __restrict__ et, const int* __restrict__ dst,
                             int* __restrict__ cs) {
    int e = blockIdx.x * 256 + threadIdx.x;
    if (e < N_EDGES) atomicAdd(&cs[dst[e] * N_RELS + et[e]], 1);
}

__global__ void scan_k1(const int* __restrict__ cs, int* __restrict__ bsum) {
    __shared__ int red[256];
    int base = blockIdx.x * 2048 + threadIdx.x * 8;
    int s = 0;
#pragma unroll
    for (int i = 0; i < 8; ++i) {
        int idx = base + i;
        if (idx < N_CELLS) s += cs[idx];
    }
    red[threadIdx.x] = s;
    __syncthreads();
    for (int off = 128; off > 0; off >>= 1) {
        if (threadIdx.x < off) red[threadIdx.x] += red[threadIdx.x + off];
        __syncthreads();
    }
    if (threadIdx.x == 0) bsum[blockIdx.x] = red[0];
}

__global__ void scan_k2(int* __restrict__ bsum) {
    __shared__ int p[1024];
    int t = threadIdx.x;
    int v = (t < SCAN_NB) ? bsum[t] : 0;
    p[t] = v;
    __syncthreads();
    for (int off = 1; off < 1024; off <<= 1) {
        int a = (t >= off) ? p[t - off] : 0;
        __syncthreads();
        p[t] += a;
        __syncthreads();
    }
    if (t < SCAN_NB) bsum[t] = p[t] - v;  // exclusive
}

__global__ void scan_k3(int* __restrict__ cs, const int* __restrict__ bsum) {
    __shared__ int red[256];
    int base = blockIdx.x * 2048 + threadIdx.x * 8;
    int v[8];
    int s = 0;
#pragma unroll
    for (int i = 0; i < 8; ++i) {
        int idx = base + i;
        v[i] = (idx < N_CELLS) ? cs[idx] : 0;
        s += v[i];
    }
    red[threadIdx.x] = s;
    __syncthreads();
    for (int off = 1; off < 256; off <<= 1) {
        int a = (threadIdx.x >= off) ? red[threadIdx.x - off] : 0;
        __syncthreads();
        red[threadIdx.x] += a;
        __syncthreads();
    }
    int run = bsum[blockIdx.x] + red[threadIdx.x] - s;  // exclusive within grid
#pragma unroll
    for (int i = 0; i < 8; ++i) {
        int idx = base + i;
        if (idx < N_CELLS) cs[idx] = run;
        run += v[i];
    }
}

// destructive scatter: cs[m] ends as end-offset of cell m (= start of m+1)
__global__ void scatter_kernel(const int* __restrict__ src, const int* __restrict__ dst,
                               const int* __restrict__ et, int* __restrict__ cs,
                               unsigned* __restrict__ rec) {
    int e = blockIdx.x * 256 + threadIdx.x;
    if (e < N_EDGES) {
        int pos = atomicAdd(&cs[dst[e] * N_RELS + et[e]], 1);
        rec[pos] = (unsigned)src[e];
    }
}

// ---------------- weight prep ----------------

// Wt[r][o][f] = W1[r][f][o] (r<20), root1 (r==20), bf16
__global__ void wt_convert(const float* __restrict__ W1, const float* __restrict__ root1,
                           __hip_bfloat16* __restrict__ Wt) {
    int r = blockIdx.x;  // 0..20
    const float* src = (r < N_RELS) ? (W1 + (size_t)r * F_IN * HID) : root1;
    for (int i = threadIdx.x; i < F_IN * HID; i += 256) {
        int f = i >> 4, o = i & 15;
        Wt[((size_t)r * HID + o) * F_IN + f] = __float2bfloat16(src[i]);
    }
}

// W2t[p][oc][k]: p<10 -> rel pair (2p, 2p+1) along k (k<16 -> rel 2p, else 2p+1);
// p==10 -> root2 in k<16, zeros in k>=16
__global__ void wt2_convert(const float* __restrict__ W2, const float* __restrict__ root2,
                            __hip_bfloat16* __restrict__ W2t) {
    int i = blockIdx.x * 256 + threadIdx.x;  // over 11*32*32
    if (i < 11 * 32 * 32) {
        int p = i >> 10, oc = (i >> 5) & 31, k = i & 31;
        float v;
        if (p == 10) v = (k < 16) ? root2[k * N_CLASSES + oc] : 0.f;
        else v = W2[((size_t)(2 * p + (k >> 4)) * HID + (k & 15)) * N_CLASSES + oc];
        W2t[i] = __float2bfloat16(v);
    }
}

// ---------------- conv1 ----------------

// h1[r][n][16] bf16 for r<20; r==20 (root1) -> agg1 fp32 (+b1)
__global__ __launch_bounds__(256) void xform_gemm(const float* __restrict__ x,
                                                  const __hip_bfloat16* __restrict__ Wt,
                                                  const float* __restrict__ b1,
                                                  __hip_bfloat16* __restrict__ h1,
                                                  float* __restrict__ agg1) {
    int wave = threadIdx.x >> 6;
    int lane = threadIdx.x & 63;
    int col = lane & 15;
    int kgrp = lane >> 4;
    int node = blockIdx.x * 64 + wave * 16 + col;
    bool valid = node < N_NODES;

    bf16x8 xf[4];
    const float* xrow = x + (size_t)node * F_IN;
#pragma unroll
    for (int s = 0; s < 4; ++s) {
        int k0 = s * 32 + kgrp * 8;
        float4 a = valid ? *(const float4*)(xrow + k0)     : float4{0.f, 0.f, 0.f, 0.f};
        float4 b = valid ? *(const float4*)(xrow + k0 + 4) : float4{0.f, 0.f, 0.f, 0.f};
        bf16x8 v;
        v[0] = f2bf(a.x); v[1] = f2bf(a.y); v[2] = f2bf(a.z); v[3] = f2bf(a.w);
        v[4] = f2bf(b.x); v[5] = f2bf(b.y); v[6] = f2bf(b.z); v[7] = f2bf(b.w);
        xf[s] = v;
    }

    for (int r = 0; r < N_RELS + 1; ++r) {
        f32x4 acc = {0.f, 0.f, 0.f, 0.f};
        const __hip_bfloat16* wr = Wt + ((size_t)r * HID + col) * F_IN;
#pragma unroll
        for (int s = 0; s < 4; ++s) {
            bf16x8 wf = *(const bf16x8*)(wr + s * 32 + kgrp * 8);
            acc = __builtin_amdgcn_mfma_f32_16x16x32_bf16(wf, xf[s], acc, 0, 0, 0);
        }
        if (valid) {
            if (r < N_RELS) {
                union { ushort4 u4; short s4[4]; } o;
                o.s4[0] = f2bf(acc[0]); o.s4[1] = f2bf(acc[1]);
                o.s4[2] = f2bf(acc[2]); o.s4[3] = f2bf(acc[3]);
                *(ushort4*)(h1 + ((size_t)r * N_NODES + node) * HID + kgrp * 4) = o.u4;
            } else {
                int c0 = kgrp * 4;
                float4 o = {acc[0] + b1[c0], acc[1] + b1[c0 + 1],
                            acc[2] + b1[c0 + 2], acc[3] + b1[c0 + 3]};
                *(float4*)(agg1 + (size_t)node * HID + c0) = o;
            }
        }
    }
}

// per-dst aggregation over cells; fused BN1 stats
__global__ __launch_bounds__(256) void conv1_agg(const __hip_bfloat16* __restrict__ h1,
                                                 const unsigned* __restrict__ rec,
                                                 const int* __restrict__ cs,
                                                 float* __restrict__ agg1,
                                                 float* __restrict__ st1) {
    __shared__ float ls[HID], lq[HID];
    if (threadIdx.x < HID) { ls[threadIdx.x] = 0.f; lq[threadIdx.x] = 0.f; }
    __syncthreads();
    int j = threadIdx.x & 15, grp = threadIdx.x >> 4;
    int d = blockIdx.x * 16 + grp;
    float v = 0.f;
    if (d < N_NODES) {
        int m0 = d * N_RELS;
        int prev = (d == 0) ? 0 : cs[m0 - 1];
        float acc = 0.f;
        for (int r = 0; r < N_RELS; ++r) {
            int cur = cs[m0 + r];
            if (cur > prev) {
                float s = 0.f;
                for (int i = prev; i < cur; ++i) {
                    int sn = rec[i];
                    s += __bfloat162float(h1[((size_t)r * N_NODES + sn) * HID + j]);
                }
                acc = fmaf(s, 1.0f / (float)(cur - prev), acc);
            }
            prev = cur;
        }
        size_t o = (size_t)d * HID + j;
        v = agg1[o] + acc;
        agg1[o] = v;
    }
    atomicAdd(&ls[j], v);
    atomicAdd(&lq[j], v * v);
    __syncthreads();
    if (threadIdx.x < HID) {
        atomicAdd(&st1[threadIdx.x], ls[threadIdx.x]);
        atomicAdd(&st1[HID + threadIdx.x], lq[threadIdx.x]);
    }
}

// BN1 + ReLU -> bf16 into regionX slot 20
__global__ void bn_relu1(const float* __restrict__ a, const float* __restrict__ stats,
                         const float* __restrict__ gamma, const float* __restrict__ beta,
                         __hip_bfloat16* __restrict__ hb) {
    int i = blockIdx.x * 256 + threadIdx.x;
    if (i < N_NODES * HID) {
        int j = i & (HID - 1);
        float mean = stats[j] * (1.0f / N_NODES);
        float var = stats[HID + j] * (1.0f / N_NODES) - mean * mean;
        float rs = rsqrtf(var + BN_EPS);
        float val = (a[i] - mean) * rs * gamma[j] + beta[j];
        hb[i] = __float2bfloat16(fmaxf(val, 0.f));
    }
}

// ---------------- conv2 ----------------

// per-(dst,rel) mean of hbn (bf16) -> regionX slots 0..19 (dense, zeros for empty cells)
__global__ __launch_bounds__(256) void conv2_agg(const __hip_bfloat16* __restrict__ hbnb,
                                                 const unsigned* __restrict__ rec,
                                                 const int* __restrict__ cs,
                                                 __hip_bfloat16* __restrict__ agg2) {
    int j = threadIdx.x & 15, grp = threadIdx.x >> 4;
    int d = blockIdx.x * 16 + grp;
    if (d >= N_NODES) return;
    int m0 = d * N_RELS;
    int prev = (d == 0) ? 0 : cs[m0 - 1];
    for (int r = 0; r < N_RELS; ++r) {
        int cur = cs[m0 + r];
        float ov = 0.f;
        if (cur > prev) {
            float s = 0.f;
            for (int i = prev; i < cur; ++i)
                s += __bfloat162float(hbnb[(size_t)rec[i] * HID + j]);
            ov = s * (1.0f / (float)(cur - prev));
        }
        agg2[((size_t)r * N_NODES + d) * HID + j] = __float2bfloat16(ov);
        prev = cur;
    }
}

// buf2[n][c] = sum_p mfma over relation pairs (+ root2 via slot 20) + b2
__global__ __launch_bounds__(256) void gemm2(const __hip_bfloat16* __restrict__ agg2,
                                             const __hip_bfloat16* __restrict__ W2t,
                                             const float* __restrict__ b2,
                                             float* __restrict__ buf2) {
    int wave = threadIdx.x >> 6, lane = threadIdx.x & 63;
    int col = lane & 15, kgrp = lane >> 4;
    int node = blockIdx.x * 64 + wave * 16 + col;
    bool valid = node < N_NODES;
    int nidx = valid ? node : 0;

    bf16x8 bf[11];
#pragma unroll
    for (int p = 0; p < 11; ++p) {
        int slot = 2 * p + (kgrp >> 1);
        bf[p] = *(const bf16x8*)(agg2 + ((size_t)slot * N_NODES + nidx) * HID + (kgrp & 1) * 8);
    }
#pragma unroll
    for (int ct = 0; ct < 2; ++ct) {
        f32x4 acc = {0.f, 0.f, 0.f, 0.f};
#pragma unroll
        for (int p = 0; p < 11; ++p) {
            bf16x8 wf = *(const bf16x8*)(W2t + ((size_t)p * 32 + ct * 16 + col) * 32 + kgrp * 8);
            acc = __builtin_amdgcn_mfma_f32_16x16x32_bf16(wf, bf[p], acc, 0, 0, 0);
        }
        if (valid) {
            int c0 = ct * 16 + kgrp * 4;
            float4 o = {acc[0] + b2[c0], acc[1] + b2[c0 + 1],
                        acc[2] + b2[c0 + 2], acc[3] + b2[c0 + 3]};
            *(float4*)(buf2 + (size_t)node * N_CLASSES + c0) = o;
        }
    }
}

template <int CH>
__global__ void bn_stats(const float* __restrict__ v, float* __restrict__ stats) {
    __shared__ float ls[CH], lq[CH];
    if (threadIdx.x < CH) { ls[threadIdx.x] = 0.f; lq[threadIdx.x] = 0.f; }
    __syncthreads();
    const int total = N_NODES * CH;
    int j = threadIdx.x % CH;
    float s = 0.f, q = 0.f;
    for (int i = blockIdx.x * blockDim.x + threadIdx.x; i < total; i += gridDim.x * blockDim.x) {
        float t = v[i];
        s += t; q += t * t;
    }
    atomicAdd(&ls[j], s);
    atomicAdd(&lq[j], q);
    __syncthreads();
    if (threadIdx.x < CH) {
        atomicAdd(&stats[threadIdx.x], ls[threadIdx.x]);
        atomicAdd(&stats[CH + threadIdx.x], lq[threadIdx.x]);
    }
}

__global__ void final_kernel(const float* __restrict__ buf2, const float* __restrict__ stats,
                             const float* __restrict__ gamma, const float* __restrict__ beta,
                             float* __restrict__ out) {
    int idx = blockIdx.x * 256 + threadIdx.x;  // over N*32, exact
    int j = threadIdx.x & 31;
    float mean = stats[j] * (1.0f / N_NODES);
    float var = stats[N_CLASSES + j] * (1.0f / N_NODES) - mean * mean;
    float rs = rsqrtf(var + BN_EPS);
    float v = fmaxf((buf2[idx] - mean) * rs * gamma[j] + beta[j], 0.f);
    float m = v;
#pragma unroll
    for (int o = 16; o >= 1; o >>= 1) m = fmaxf(m, __shfl_xor(m, o, 32));
    float ex = __expf(v - m);
    float ssum = ex;
#pragma unroll
    for (int o = 16; o >= 1; o >>= 1) ssum += __shfl_xor(ssum, o, 32);
    out[idx] = (v - m) - logf(ssum);
}

// ---------------- launcher ----------------
extern "C" void kernel_launch(void* const* d_in, const int* in_sizes, int n_in,
                              void* d_out, int out_size, void* d_ws, size_t ws_size,
                              hipStream_t stream) {
    const float* x      = (const float*)d_in[0];
    const int*   eidx   = (const int*)d_in[1];
    const int*   etype  = (const int*)d_in[2];
    const float* W1     = (const float*)d_in[3];
    const float* root1  = (const float*)d_in[4];
    const float* b1     = (const float*)d_in[5];
    const float* gamma1 = (const float*)d_in[6];
    const float* beta1  = (const float*)d_in[7];
    const float* W2     = (const float*)d_in[8];
    const float* root2  = (const float*)d_in[9];
    const float* b2     = (const float*)d_in[10];
    const float* gamma2 = (const float*)d_in[11];
    const float* beta2  = (const float*)d_in[12];

    const int* src = eidx;
    const int* dst = eidx + N_EDGES;

    char* ws = (char*)d_ws;
    int*      cs   = (int*)(ws + OFF_CS);
    unsigned* rec  = (unsigned*)(ws + OFF_REC);
    float*    buf2 = (float*)(ws + OFF_REC);       // overlays rec (dead after conv2_agg)
    float*    agg1 = (float*)(ws + OFF_AGG1);
    int*      bsum = (int*)(ws + OFF_BSUM);
    float*    st1  = (float*)(ws + OFF_ST1);
    float*    st2  = (float*)(ws + OFF_ST2);
    __hip_bfloat16* Wt  = (__hip_bfloat16*)(ws + OFF_WT);
    __hip_bfloat16* W2t = (__hip_bfloat16*)(ws + OFF_W2T);
    __hip_bfloat16* h1   = (__hip_bfloat16*)(ws + OFF_X);                      // slots 0..19
    __hip_bfloat16* hbnb = (__hip_bfloat16*)(ws + OFF_X + 20 * SLOT_BYTES);    // slot 20
    __hip_bfloat16* agg2 = (__hip_bfloat16*)(ws + OFF_X);                      // slots 0..21

    float* out = (float*)d_out;

    hipMemsetAsync(cs, 0, 8000000ull, stream);
    hipMemsetAsync(st1, 0, 512, stream);

    const int eblocks = (N_EDGES + 255) / 256;  // 12500
    count_kernel<<<eblocks, 256, 0, stream>>>(etype, dst, cs);
    scan_k1<<<SCAN_NB, 256, 0, stream>>>(cs, bsum);
    scan_k2<<<1, 1024, 0, stream>>>(bsum);
    scan_k3<<<SCAN_NB, 256, 0, stream>>>(cs, bsum);
    scatter_kernel<<<eblocks, 256, 0, stream>>>(src, dst, etype, cs, rec);

    wt_convert<<<N_RELS + 1, 256, 0, stream>>>(W1, root1, Wt);
    wt2_convert<<<(11 * 32 * 32 + 255) / 256, 256, 0, stream>>>(W2, root2, W2t);

    xform_gemm<<<(N_NODES + 63) / 64, 256, 0, stream>>>(x, Wt, b1, h1, agg1);
    conv1_agg<<<(N_NODES + 15) / 16, 256, 0, stream>>>(h1, rec, cs, agg1, st1);
    bn_relu1<<<(N_NODES * HID + 255) / 256, 256, 0, stream>>>(agg1, st1, gamma1, beta1, hbnb);

    conv2_agg<<<(N_NODES + 15) / 16, 256, 0, stream>>>(hbnb, rec, cs, agg2);
    gemm2<<<(N_NODES + 63) / 64, 256, 0, stream>>>(agg2, W2t, b2, buf2);
    bn_stats<N_CLASSES><<<512, 256, 0, stream>>>(buf2, st2);
    final_kernel<<<(N_NODES * N_CLASSES + 255) / 256, 256, 0, stream>>>(buf2, st2, gamma2, beta2, out);
}